// Round 15
// baseline (305.768 us; speedup 1.0000x reference)
//
#include <hip/hip_runtime.h>
#include <math.h>

#define NEG_SLOPE 0.2f

typedef short short8 __attribute__((ext_vector_type(8)));
typedef float f32x4 __attribute__((ext_vector_type(4)));

__device__ __forceinline__ float lrelu(float x){ return x > 0.f ? x : NEG_SLOPE * x; }

__device__ __forceinline__ unsigned short f2bf(float f){
  union { float f; unsigned u; } v; v.f = f;
  unsigned r = v.u + 0x7fff + ((v.u >> 16) & 1);  // RNE
  return (unsigned short)(r >> 16);
}
__device__ __forceinline__ float bf2f(unsigned short u){
  union { unsigned u; float f; } v; v.u = ((unsigned)u) << 16; return v.f;
}

__device__ __forceinline__ void gld16(const unsigned short* g, unsigned short* l){
  __builtin_amdgcn_global_load_lds(
      (const __attribute__((address_space(1))) unsigned int*)g,
      (__attribute__((address_space(3))) unsigned int*)l, 16, 0, 0);
}

#define MFMA_BF16 __builtin_amdgcn_mfma_f32_16x16x32_bf16

// ---------------- CSR build (dst-indexed) ----------------
__global__ void k_count(const int* __restrict__ dst, int* __restrict__ cnt, int E){
  int e = blockIdx.x*blockDim.x + threadIdx.x;
  if (e < E) atomicAdd(&cnt[dst[e]], 1);
}

__global__ void k_blockscan(const int* __restrict__ cnt, int* __restrict__ row,
                            int* __restrict__ aux, int n){
  __shared__ int buf[256];
  int t = threadIdx.x;
  int base = blockIdx.x * 256;
  int v = (base + t < n) ? cnt[base + t] : 0;
  buf[t] = v;
  __syncthreads();
  #pragma unroll
  for (int off = 1; off < 256; off <<= 1){
    int u = (t >= off) ? buf[t - off] : 0;
    __syncthreads();
    buf[t] += u;
    __syncthreads();
  }
  if (base + t < n) row[base + t + 1] = buf[t];
  if (t == 255) aux[blockIdx.x] = buf[255];
  if (blockIdx.x == 0 && t == 0) row[0] = 0;
}

__global__ void k_addoff(const int* __restrict__ aux, int* __restrict__ row, int n){
  __shared__ int sbuf[256];
  int b = blockIdx.x, t = threadIdx.x;
  sbuf[t] = (t < b) ? aux[t] : 0;
  __syncthreads();
  #pragma unroll
  for (int off = 128; off >= 1; off >>= 1){
    if (t < off) sbuf[t] += sbuf[t + off];
    __syncthreads();
  }
  int i = b * 256 + t;
  if (i < n) row[i + 1] += sbuf[0];
}

__global__ void k_scatter(const int* __restrict__ src, const int* __restrict__ dst,
                          const int* __restrict__ row, int* __restrict__ cur,
                          int* __restrict__ csr, int E){
  int e = blockIdx.x*blockDim.x + threadIdx.x;
  if (e < E){
    int d = dst[e];
    int p = atomicAdd(&cur[d], 1);
    csr[row[d] + p] = src[e];
  }
}

// ------- fused prep: x->bf16 + 3 weight transposes + layer-1 attention fold -------
__global__ void k_prep(const float* __restrict__ x, unsigned short* __restrict__ xb, int nx, int nxb,
                       const float* __restrict__ W1, unsigned short* __restrict__ Wt1,
                       const float* __restrict__ W2, unsigned short* __restrict__ Wt2,
                       const float* __restrict__ W3, unsigned short* __restrict__ Wt3,
                       const float* __restrict__ a_s1, const float* __restrict__ a_d1,
                       float* __restrict__ ws1){
  __shared__ float tile[32][33];
  int b = blockIdx.x, t = threadIdx.x;
  if (b < nxb){
    int i0 = b * 2048 + t * 8;
    if (i0 + 8 <= nx){
      float4 f0 = *reinterpret_cast<const float4*>(x + i0);
      float4 f1 = *reinterpret_cast<const float4*>(x + i0 + 4);
      short8 o;
      o[0]=f2bf(f0.x); o[1]=f2bf(f0.y); o[2]=f2bf(f0.z); o[3]=f2bf(f0.w);
      o[4]=f2bf(f1.x); o[5]=f2bf(f1.y); o[6]=f2bf(f1.z); o[7]=f2bf(f1.w);
      *reinterpret_cast<short8*>(xb + i0) = o;
    } else {
      for (int k = 0; k < 8 && i0 + k < nx; ++k) xb[i0 + k] = f2bf(x[i0 + k]);
    }
    return;
  }
  int bp = b - nxb;
  if (bp >= 64 + 1024 + 128){
    int k = bp - (64 + 1024 + 128);
    int h = t >> 5, lq = t & 31;
    float4 wv = *reinterpret_cast<const float4*>(&W1[(size_t)k * 1024 + h * 128 + lq * 4]);
    float4 sv = *reinterpret_cast<const float4*>(&a_s1[h * 128 + lq * 4]);
    float4 dv = *reinterpret_cast<const float4*>(&a_d1[h * 128 + lq * 4]);
    float ps = wv.x*sv.x + wv.y*sv.y + wv.z*sv.z + wv.w*sv.w;
    float pd = wv.x*dv.x + wv.y*dv.y + wv.z*dv.z + wv.w*dv.w;
    #pragma unroll
    for (int off = 16; off >= 1; off >>= 1){
      ps += __shfl_xor(ps, off);
      pd += __shfl_xor(pd, off);
    }
    if (lq == 0){ ws1[k * 16 + h] = ps; ws1[k * 16 + 8 + h] = pd; }
    return;
  }
  const float* W; unsigned short* Wt; int K, N, ti;
  if (bp < 64)            { W = W1; Wt = Wt1; K = 64;   N = 1024; ti = bp;
                            int kb = (ti & 1) * 32, nb = (ti >> 1) * 32;
                            int tx = t & 31, ty = t >> 5;
                            #pragma unroll
                            for (int i = ty; i < 32; i += 8) tile[i][tx] = W[(size_t)(kb+i)*N + nb+tx];
                            __syncthreads();
                            #pragma unroll
                            for (int i = ty; i < 32; i += 8) Wt[(size_t)(nb+i)*K + kb+tx] = f2bf(tile[tx][i]);
                            return; }
  if (bp < 64 + 1024)     { W = W2; Wt = Wt2; K = 1024; N = 1024; ti = bp - 64; }
  else                    { W = W3; Wt = Wt3; K = 1024; N = 128;  ti = bp - 64 - 1024; }
  int kb = (ti & 31) * 32, nb = (ti >> 5) * 32;
  int tx = t & 31, ty = t >> 5;
  #pragma unroll
  for (int i = ty; i < 32; i += 8) tile[i][tx] = W[(size_t)(kb+i)*N + nb+tx];
  __syncthreads();
  #pragma unroll
  for (int i = ty; i < 32; i += 8) Wt[(size_t)(nb+i)*K + kb+tx] = f2bf(tile[tx][i]);
}

// ---------------- layer-1 logits ----------------
__global__ void k_logits1(const unsigned short* __restrict__ xb, const float* __restrict__ ws,
                          float* __restrict__ ALS, float* __restrict__ ALD, int N){
  __shared__ unsigned short lx[32 * 64];
  __shared__ float lw[64 * 16];
  int t = threadIdx.x;
  int n0 = blockIdx.x * 32;
  int r = t >> 3, c = (t & 7) * 8;
  if (n0 + r < N)
    *reinterpret_cast<short8*>(&lx[r * 64 + c]) =
      *reinterpret_cast<const short8*>(&xb[(size_t)(n0 + r) * 64 + c]);
  else {
    short8 z = {0,0,0,0,0,0,0,0};
    *reinterpret_cast<short8*>(&lx[r * 64 + c]) = z;
  }
  *reinterpret_cast<float4*>(&lw[t * 4]) = *reinterpret_cast<const float4*>(&ws[t * 4]);
  __syncthreads();
  int nl = t >> 3, h = t & 7;
  if (n0 + nl >= N) return;
  float s = 0.f, d = 0.f;
  #pragma unroll 8
  for (int k = 0; k < 64; ++k){
    float xv = bf2f(lx[nl * 64 + k]);
    s = fmaf(xv, lw[k * 16 + h], s);
    d = fmaf(xv, lw[k * 16 + 8 + h], d);
  }
  ALS[(size_t)(n0 + nl) * 8 + h] = s;
  ALD[(size_t)(n0 + nl) * 8 + h] = d;
}

// ------- softmax precompute; TR=0: alpha[j*H+h], TR=1: alpha[h*E+j] (head-major) -------
template<int HEADS, int TR>
__global__ void k_sm(const float* __restrict__ ALS, const float* __restrict__ ALD,
                     const int* __restrict__ row, const int* __restrict__ csr,
                     float* __restrict__ alpha, float* __restrict__ alps,
                     float* __restrict__ invl, int N, int E){
  int idx = blockIdx.x * blockDim.x + threadIdx.x;
  int n = idx / HEADS, h = idx - n * HEADS;
  if (n >= N) return;
  float ald = ALD[(size_t)n * HEADS + h];
  float es = lrelu(ALS[(size_t)n * HEADS + h] + ald);   // self-loop logit
  float m = es;
  int beg = row[n], end = row[n + 1];
  for (int j = beg; j < end; ++j)
    m = fmaxf(m, lrelu(ALS[(size_t)csr[j] * HEADS + h] + ald));
  float ps = __expf(es - m);
  float l = ps;
  for (int j = beg; j < end; ++j){
    float p = __expf(lrelu(ALS[(size_t)csr[j] * HEADS + h] + ald) - m);
    if (TR) alpha[(size_t)h * E + j] = p;
    else    alpha[(size_t)j * HEADS + h] = p;
    l += p;
  }
  alps[(size_t)n * HEADS + h] = ps;
  invl[(size_t)n * HEADS + h] = 1.f / l;
}

// ---------------- layer-1 gather on x: pure weighted sum ----------------
__global__ void k_gat_x(const unsigned short* __restrict__ xb, const float* __restrict__ alpha,
                        const float* __restrict__ alps, const float* __restrict__ invl,
                        const int* __restrict__ row, const int* __restrict__ csr,
                        unsigned short* __restrict__ G, int N){
  int t = threadIdx.x;
  int n = blockIdx.x * 4 + (t >> 6);
  if (n >= N) return;
  int lane = t & 63;
  float xv = bf2f(xb[(size_t)n * 64 + lane]);
  float4 s0 = *reinterpret_cast<const float4*>(&alps[(size_t)n * 8]);
  float4 s1 = *reinterpret_cast<const float4*>(&alps[(size_t)n * 8 + 4]);
  float acc[8] = {s0.x*xv, s0.y*xv, s0.z*xv, s0.w*xv, s1.x*xv, s1.y*xv, s1.z*xv, s1.w*xv};
  int beg = row[n], end = row[n + 1];
  for (int j = beg; j < end; ++j){
    int s = csr[j];
    float xs = bf2f(xb[(size_t)s * 64 + lane]);
    float4 a0 = *reinterpret_cast<const float4*>(&alpha[(size_t)j * 8]);
    float4 a1 = *reinterpret_cast<const float4*>(&alpha[(size_t)j * 8 + 4]);
    acc[0] = fmaf(a0.x, xs, acc[0]);
    acc[1] = fmaf(a0.y, xs, acc[1]);
    acc[2] = fmaf(a0.z, xs, acc[2]);
    acc[3] = fmaf(a0.w, xs, acc[3]);
    acc[4] = fmaf(a1.x, xs, acc[4]);
    acc[5] = fmaf(a1.y, xs, acc[5]);
    acc[6] = fmaf(a1.z, xs, acc[6]);
    acc[7] = fmaf(a1.w, xs, acc[7]);
  }
  float4 i0 = *reinterpret_cast<const float4*>(&invl[(size_t)n * 8]);
  float4 i1 = *reinterpret_cast<const float4*>(&invl[(size_t)n * 8 + 4]);
  float iv[8] = {i0.x, i0.y, i0.z, i0.w, i1.x, i1.y, i1.z, i1.w};
  #pragma unroll
  for (int h = 0; h < 8; ++h)
    G[(size_t)n * 512 + h * 64 + lane] = f2bf(acc[h] * iv[h]);
}

// ---------------- layer-1 GEMM (K=64 per head) ----------------
__global__ __launch_bounds__(256) void k_gemm_g(
    const unsigned short* __restrict__ G,    // [M,512] bf16
    const unsigned short* __restrict__ Bt,   // Wt1 [1024,64] bf16
    const float* __restrict__ bias,          // [1024]
    unsigned short* __restrict__ C,          // [M,1024] bf16
    int M){
  __shared__ unsigned short As[128 * 32];
  __shared__ unsigned short Bs[128 * 32];
  const int nwg = gridDim.x;
  int bid = blockIdx.x;
  int swz = ((nwg & 7) == 0) ? ((bid & 7) * (nwg >> 3) + (bid >> 3)) : bid;
  const int head = swz % 8, byi = swz / 8;
  const int bm = byi * 128, bn = head * 128;
  const int tid  = threadIdx.x;
  const int lane = tid & 63, wave = tid >> 6;
  const int wr = wave >> 1, wc = wave & 1;
  const int lr = lane & 15, lk = lane >> 4;
  const int srow = wave * 16 + (lane >> 2);
  const int skc  = (lane & 3) * 8;
  int ar0 = bm + srow;      if (ar0 >= M) ar0 = M - 1;
  int ar1 = bm + srow + 64; if (ar1 >= M) ar1 = M - 1;
  const unsigned short* ga0 = G + (size_t)ar0 * 512 + head * 64 + skc;
  const unsigned short* ga1 = G + (size_t)ar1 * 512 + head * 64 + skc;
  const unsigned short* gb0 = Bt + (size_t)(bn + srow) * 64 + skc;
  const unsigned short* gb1 = Bt + (size_t)(bn + srow + 64) * 64 + skc;
  f32x4 acc[4][4] = {};
  #pragma unroll
  for (int k0 = 0; k0 < 64; k0 += 32){
    gld16(ga0 + k0, &As[(size_t)wave * 512]);
    gld16(ga1 + k0, &As[(size_t)(wave + 4) * 512]);
    gld16(gb0 + k0, &Bs[(size_t)wave * 512]);
    gld16(gb1 + k0, &Bs[(size_t)(wave + 4) * 512]);
    __syncthreads();
    short8 af[4], bg[4];
    #pragma unroll
    for (int m = 0; m < 4; ++m)
      af[m] = *reinterpret_cast<const short8*>(&As[(wr * 64 + m * 16 + lr) * 32 + lk * 8]);
    #pragma unroll
    for (int n = 0; n < 4; ++n)
      bg[n] = *reinterpret_cast<const short8*>(&Bs[(wc * 64 + n * 16 + lr) * 32 + lk * 8]);
    #pragma unroll
    for (int m = 0; m < 4; ++m)
      #pragma unroll
      for (int n = 0; n < 4; ++n)
        acc[m][n] = MFMA_BF16(af[m], bg[n], acc[m][n], 0, 0, 0);
    __syncthreads();
  }
  float bv[4];
  #pragma unroll
  for (int n = 0; n < 4; ++n) bv[n] = bias[bn + wc * 64 + n * 16 + lr];
  #pragma unroll
  for (int m = 0; m < 4; ++m){
    #pragma unroll
    for (int j = 0; j < 4; ++j){
      int rowi = bm + wr * 64 + m * 16 + lk * 4 + j;
      if (rowi < M){
        #pragma unroll
        for (int n = 0; n < 4; ++n)
          C[(size_t)rowi * 1024 + bn + wc * 64 + n * 16 + lr] = f2bf(fmaxf(acc[m][n][j] + bv[n], 0.f));
      }
    }
  }
}

// ---------------- m97-style GEMM + fused logits (layer 3) ----------------
template<int HEADS>
__global__ __launch_bounds__(256) void k_gemm_fused(
    const unsigned short* __restrict__ A, const unsigned short* __restrict__ Bt,
    unsigned short* __restrict__ C,
    const float* __restrict__ a_s, const float* __restrict__ a_d,
    float* __restrict__ ALS, float* __restrict__ ALD,
    int M, int N, int K, int gxc){
  __shared__ unsigned short SMEM[2 * 128 * 32];
  unsigned short* As = SMEM;
  unsigned short* Bs = SMEM + 128 * 32;
  const int nwg = gridDim.x;
  int bid = blockIdx.x;
  int swz = ((nwg & 7) == 0) ? ((bid & 7) * (nwg >> 3) + (bid >> 3)) : bid;
  const int bxi = swz % gxc, byi = swz / gxc;
  const int bm = byi * 128, bn = bxi * 128;
  const int head = bxi;
  const int tid  = threadIdx.x;
  const int lane = tid & 63, wave = tid >> 6;
  const int wr = wave >> 1, wc = wave & 1;
  const int lr = lane & 15, lk = lane >> 4;
  const int srow = wave * 16 + (lane >> 2);
  const int skc  = (lane & 3) * 8;
  int ar0 = bm + srow;      if (ar0 >= M) ar0 = M - 1;
  int ar1 = bm + srow + 64; if (ar1 >= M) ar1 = M - 1;
  const unsigned short* ga0 = A  + (size_t)ar0 * K + skc;
  const unsigned short* ga1 = A  + (size_t)ar1 * K + skc;
  const unsigned short* gb0 = Bt + (size_t)(bn + srow) * K + skc;
  const unsigned short* gb1 = Bt + (size_t)(bn + srow + 64) * K + skc;
  f32x4 acc[4][4] = {};
  for (int k0 = 0; k0 < K; k0 += 32){
    gld16(ga0 + k0, &As[(size_t)wave * 512]);
    gld16(ga1 + k0, &As[(size_t)(wave + 4) * 512]);
    gld16(gb0 + k0, &Bs[(size_t)wave * 512]);
    gld16(gb1 + k0, &Bs[(size_t)(wave + 4) * 512]);
    __syncthreads();
    short8 af[4], bg[4];
    #pragma unroll
    for (int m = 0; m < 4; ++m)
      af[m] = *reinterpret_cast<const short8*>(&As[(wr * 64 + m * 16 + lr) * 32 + lk * 8]);
    #pragma unroll
    for (int n = 0; n < 4; ++n)
      bg[n] = *reinterpret_cast<const short8*>(&Bs[(wc * 64 + n * 16 + lr) * 32 + lk * 8]);
    #pragma unroll
    for (int m = 0; m < 4; ++m)
      #pragma unroll
      for (int n = 0; n < 4; ++n)
        acc[m][n] = MFMA_BF16(af[m], bg[n], acc[m][n], 0, 0, 0);
    __syncthreads();
  }
  #pragma unroll
  for (int m = 0; m < 4; ++m){
    #pragma unroll
    for (int j = 0; j < 4; ++j){
      int rowi = bm + wr * 64 + m * 16 + lk * 4 + j;
      if (rowi < M){
        #pragma unroll
        for (int n = 0; n < 4; ++n)
          C[(size_t)rowi * N + bn + wc * 64 + n * 16 + lr] = f2bf(acc[m][n][j]);
      }
    }
  }
  float as4[4], ad4[4];
  #pragma unroll
  for (int n = 0; n < 4; ++n){
    as4[n] = a_s[head * 128 + wc * 64 + n * 16 + lr];
    ad4[n] = a_d[head * 128 + wc * 64 + n * 16 + lr];
  }
  float* red = (float*)SMEM;
  #pragma unroll
  for (int m = 0; m < 4; ++m){
    #pragma unroll
    for (int j = 0; j < 4; ++j){
      float ps = 0.f;
      #pragma unroll
      for (int n = 0; n < 4; ++n) ps = fmaf(acc[m][n][j], as4[n], ps);
      red[(wr * 64 + m * 16 + lk * 4 + j) * 32 + wc * 16 + lr] = ps;
    }
  }
  __syncthreads();
  if (tid < 128){
    float s = 0.f;
    #pragma unroll
    for (int i = 0; i < 32; ++i) s += red[tid * 32 + ((i + tid) & 31)];
    int gr = bm + tid;
    if (gr < M) ALS[(size_t)gr * HEADS + head] = s;
  }
  __syncthreads();
  #pragma unroll
  for (int m = 0; m < 4; ++m){
    #pragma unroll
    for (int j = 0; j < 4; ++j){
      float pd = 0.f;
      #pragma unroll
      for (int n = 0; n < 4; ++n) pd = fmaf(acc[m][n][j], ad4[n], pd);
      red[(wr * 64 + m * 16 + lk * 4 + j) * 32 + wc * 16 + lr] = pd;
    }
  }
  __syncthreads();
  if (tid < 128){
    float s = 0.f;
    #pragma unroll
    for (int i = 0; i < 32; ++i) s += red[tid * 32 + ((i + tid) & 31)];
    int gr = bm + tid;
    if (gr < M) ALD[(size_t)gr * HEADS + head] = s;
  }
}

// ---- 256x256 bf16 GEMM + fused logits (layer 2); read-all-early, 3-barrier tiles ----
// Per K-tile: P1 issues ALL 12 ds_reads + 2 B-stages, then barrier+lgkmcnt(0) (all
// waves' reads complete after the P1-end barrier) -> P2-P4 are pure register MFMA +
// staging with NO barriers/waits; counted vmcnt(4) once per tile. C out HEAD-MAJOR.
__global__ __launch_bounds__(512, 2) void k_gemm256p8(
    const unsigned short* __restrict__ A,   // [M,K] bf16
    const unsigned short* __restrict__ Bt,  // [N,K] bf16
    unsigned short* __restrict__ Php,       // [8][M][128] bf16 (head-major)
    const float* __restrict__ a_s, const float* __restrict__ a_d,
    float* __restrict__ ALS, float* __restrict__ ALD,   // [M,8]
    int M, int N, int K, int gxc){
  __shared__ unsigned short smem[2 * 32768];   // slot: A @0, B @16384 (elems)
  const int nwg = gridDim.x;
  int bid = blockIdx.x;
  int swz = ((nwg & 7) == 0) ? ((bid & 7) * (nwg >> 3) + (bid >> 3)) : bid;
  const int bxi = swz % gxc, byi = swz / gxc;
  const int bm = byi * 256, bn = bxi * 256;
  const int tid = threadIdx.x;
  const int lane = tid & 63, wave = tid >> 6;
  const int wr = wave >> 2, wc = wave & 3;     // 2 x 4
  const int lr = lane & 15, lk = lane >> 4;
  const int sr = tid >> 3;
  const int scol = ((tid & 7) << 3) ^ ((sr & 7) << 3);
  unsigned offA[4], offB[4];
  #pragma unroll
  for (int u = 0; u < 4; ++u){
    int r = bm + u * 64 + sr; if (r >= M) r = M - 1;
    offA[u] = (unsigned)r * (unsigned)K + scol;
    offB[u] = (unsigned)(bn + u * 64 + sr) * (unsigned)K + scol;
  }
  const int wdst = wave * 512;
  const int NKT = K >> 6;

  #define STA(T,u) gld16(A  + (size_t)offA[u] + (size_t)(T)*64, &smem[((T)&1)*32768 + (u)*4096 + wdst])
  #define STB(T,u) gld16(Bt + (size_t)offB[u] + (size_t)(T)*64, &smem[((T)&1)*32768 + 16384 + (u)*4096 + wdst])

  // prologue: A(0), B(0), A(1)
  #pragma unroll
  for (int u = 0; u < 4; ++u) STA(0, u);
  #pragma unroll
  for (int u = 0; u < 4; ++u) STB(0, u);
  #pragma unroll
  for (int u = 0; u < 4; ++u) STA(1, u);
  asm volatile("s_waitcnt vmcnt(4)" ::: "memory");
  __builtin_amdgcn_s_barrier();

  f32x4 acc[8][4] = {};
  short8 afA[4][2], afB[4][2], bg[4][2];

  #define RD_AF(dst, moff) \
    _Pragma("unroll") \
    for (int m = 0; m < 4; ++m){ \
      int row = wr * 128 + (m + (moff)) * 16 + lr; \
      int rb = row * 64, sw = (row & 7) << 3; \
      dst[m][0] = *reinterpret_cast<const short8*>(&sa[rb + ((lk * 8) ^ sw)]); \
      dst[m][1] = *reinterpret_cast<const short8*>(&sa[rb + ((32 + lk * 8) ^ sw)]); \
    }
  #define RD_BG() \
    _Pragma("unroll") \
    for (int n = 0; n < 4; ++n){ \
      int row = wc * 64 + n * 16 + lr; \
      int rb = row * 64, sw = (row & 7) << 3; \
      bg[n][0] = *reinterpret_cast<const short8*>(&sb[rb + ((lk * 8) ^ sw)]); \
      bg[n][1] = *reinterpret_cast<const short8*>(&sb[rb + ((32 + lk * 8) ^ sw)]); \
    }
  #define QUADX(src, mb, nb) \
    _Pragma("unroll") \
    for (int m = 0; m < 4; ++m) \
      _Pragma("unroll") \
      for (int n = 0; n < 2; ++n){ \
        acc[(mb)+m][(nb)+n] = MFMA_BF16(src[m][0], bg[(nb)+n][0], acc[(mb)+m][(nb)+n], 0, 0, 0); \
        acc[(mb)+m][(nb)+n] = MFMA_BF16(src[m][1], bg[(nb)+n][1], acc[(mb)+m][(nb)+n], 0, 0, 0); \
      }

  for (int kt = 0; kt < NKT; ++kt){
    const unsigned short* sa = &smem[(kt & 1) * 32768];
    const unsigned short* sb = sa + 16384;
    // ---- P1: issue ALL reads; stage B(kt+1) u0,u1; drain reads; MFMA Q1 ----
    RD_AF(afA, 0);
    RD_AF(afB, 4);
    RD_BG();
    if (kt + 1 < NKT){ STB(kt + 1, 0); STB(kt + 1, 1); }
    __builtin_amdgcn_s_barrier();
    asm volatile("s_waitcnt lgkmcnt(0)" ::: "memory");
    __builtin_amdgcn_sched_barrier(0);
    __builtin_amdgcn_s_setprio(1);
    QUADX(afA, 0, 0);
    __builtin_amdgcn_s_setprio(0);
    __builtin_amdgcn_s_barrier();
    // after this barrier: every wave's LDS reads of slot s are complete.
    // ---- P2: stage B(kt+1) u2,u3; MFMA Q2 (registers only) ----
    if (kt + 1 < NKT){ STB(kt + 1, 2); STB(kt + 1, 3); }
    __builtin_amdgcn_s_setprio(1);
    QUADX(afA, 0, 2);
    __builtin_amdgcn_s_setprio(0);
    // ---- P3: stage A(kt+2) u0,u2; MFMA Q3 ----
    if (kt + 2 < NKT){ STA(kt + 2, 0); STA(kt + 2, 2); }
    __builtin_amdgcn_s_setprio(1);
    QUADX(afB, 4, 0);
    __builtin_amdgcn_s_setprio(0);
    // ---- P4: stage A(kt+2) u1,u3; MFMA Q4; counted vmcnt; slot swap ----
    if (kt + 2 < NKT){ STA(kt + 2, 1); STA(kt + 2, 3); }
    __builtin_amdgcn_s_setprio(1);
    QUADX(afB, 4, 2);
    __builtin_amdgcn_s_setprio(0);
    asm volatile("s_waitcnt vmcnt(4)" ::: "memory");
    __builtin_amdgcn_s_barrier();
  }

  // ---- C store (bf16, head-major) ----
  const int hloc = wc >> 1;
  const int head = bxi * 2 + hloc;
  const int cc = (wc & 1) * 64;
  #pragma unroll
  for (int m = 0; m < 8; ++m){
    #pragma unroll
    for (int j = 0; j < 4; ++j){
      int row = bm + wr * 128 + m * 16 + lk * 4 + j;
      if (row < M){
        #pragma unroll
        for (int n = 0; n < 4; ++n)
          Php[((size_t)head * M + row) * 128 + cc + n * 16 + lr] = f2bf(acc[m][n][j]);
      }
    }
  }
  // ---- fused logits (2 heads per block) ----
  float as4[4], ad4[4];
  #pragma unroll
  for (int n = 0; n < 4; ++n){
    as4[n] = a_s[head * 128 + cc + n * 16 + lr];
    ad4[n] = a_d[head * 128 + cc + n * 16 + lr];
  }
  asm volatile("s_waitcnt vmcnt(0)" ::: "memory");   // drain tail stages before LDS reuse
  __builtin_amdgcn_s_barrier();
  float2* red = (float2*)smem;
  __syncthreads();
  #pragma unroll
  for (int hh = 0; hh < 2; ++hh){
    if (hloc == hh){
      #pragma unroll
      for (int m = 0; m < 8; ++m){
        #pragma unroll
        for (int j = 0; j < 4; ++j){
          float ps = 0.f, pd = 0.f;
          #pragma unroll
          for (int n = 0; n < 4; ++n){
            ps = fmaf(acc[m][n][j], as4[n], ps);
            pd = fmaf(acc[m][n][j], ad4[n], pd);
          }
          red[(wr * 128 + m * 16 + lk * 4 + j) * 32 + (wc & 1) * 16 + lr] = make_float2(ps, pd);
        }
      }
    }
    __syncthreads();
    if (tid < 256){
      float ss = 0.f, sd = 0.f;
      #pragma unroll
      for (int i = 0; i < 32; ++i){
        float2 v = red[tid * 32 + ((i + tid) & 31)];
        ss += v.x; sd += v.y;
      }
      int gr = bm + tid;
      if (gr < M){
        ALS[(size_t)gr * 8 + bxi * 2 + hh] = ss;
        ALD[(size_t)gr * 8 + bxi * 2 + hh] = sd;
      }
    }
    __syncthreads();
  }
  #undef STA
  #undef STB
  #undef RD_AF
  #undef RD_BG
  #undef QUADX
}

// --- layer-2 gather, head-major: one head per block; head = bid&7 (XCD affinity) ---
__global__ void k_gat2h(const unsigned short* __restrict__ Php,  // [8][N][128] bf16
                        const float* __restrict__ alpha,         // [8][E] (head-major)
                        const float* __restrict__ alps, const float* __restrict__ invl, // [N,8]
                        const int* __restrict__ row, const int* __restrict__ csr,
                        const float* __restrict__ bias, unsigned short* __restrict__ outv,
                        int N, int E){
  int h = blockIdx.x & 7;
  int nb = blockIdx.x >> 3;
  int t = threadIdx.x;            // 256 = 16 nodes x 16 threads
  int n = nb * 16 + (t >> 4);
  if (n >= N) return;
  int c0 = (t & 15) * 8;
  const unsigned short* hb = Php + (size_t)h * N * 128;
  const float* alp = alpha + (size_t)h * E;
  float sp = alps[(size_t)n * 8 + h];
  short8 hv8 = *reinterpret_cast<const short8*>(hb + (size_t)n * 128 + c0);
  float accA[8], accB[8] = {};
  #pragma unroll
  for (int v = 0; v < 8; ++v) accA[v] = sp * bf2f((unsigned short)hv8[v]);
  int beg = row[n], end = row[n + 1];
  int j = beg;
  for (; j + 1 < end; j += 2){
    int s0 = csr[j], s1 = csr[j + 1];
    float p0 = alp[j], p1 = alp[j + 1];
    short8 v0 = *reinterpret_cast<const short8*>(hb + (size_t)s0 * 128 + c0);
    short8 v1 = *reinterpret_cast<const short8*>(hb + (size_t)s1 * 128 + c0);
    #pragma unroll
    for (int v = 0; v < 8; ++v){
      accA[v] = fmaf(p0, bf2f((unsigned short)v0[v]), accA[v]);
      accB[v] = fmaf(p1, bf2f((unsigned short)v1[v]), accB[v]);
    }
  }
  if (j < end){
    int s0 = csr[j];
    float p0 = alp[j];
    short8 v0 = *reinterpret_cast<const short8*>(hb + (size_t)s0 * 128 + c0);
    #pragma unroll
    for (int v = 0; v < 8; ++v) accA[v] = fmaf(p0, bf2f((unsigned short)v0[v]), accA[v]);
  }
  float inv = invl[(size_t)n * 8 + h];
  size_t ob = ((size_t)n * 8 + h) * 128 + c0;
  #pragma unroll
  for (int v = 0; v < 8; ++v){
    float o = fmaxf((accA[v] + accB[v]) * inv + bias[h * 128 + c0 + v], 0.f);
    outv[ob + v] = f2bf(o);
  }
}

// ------- fused layer-3 gather (inline softmax, used nodes only) + MLP scorer -------
__global__ void k_pair(const unsigned short* __restrict__ hp,   // P3 [N,128] bf16
                       const float* __restrict__ al, const float* __restrict__ aldv,  // [N]
                       const int* __restrict__ row, const int* __restrict__ csr,
                       const float* __restrict__ bias,          // b3 [128]
                       const int* __restrict__ liq, const int* __restrict__ ing,
                       const float* __restrict__ mw1, const float* __restrict__ mb1,
                       const float* __restrict__ mw2, const float* __restrict__ mb2,
                       const float* __restrict__ mw3, const float* __restrict__ mb3,
                       float* __restrict__ out, int B){
  __shared__ float pairv[256];
  __shared__ float z1[128];
  __shared__ float z2[64];
  int r = blockIdx.x;
  int t = threadIdx.x;            // 128: wave0 = liq node, wave1 = ing node
  int w = t >> 6;
  int lane = t & 63;
  int n = w ? ing[r] : liq[r];
  float ald = aldv[n];
  float es = lrelu(al[n] + ald);
  int beg = row[n], end = row[n + 1];
  float m = es;
  for (int j = beg; j < end; ++j)
    m = fmaxf(m, lrelu(al[csr[j]] + ald));
  float ps = __expf(es - m);
  float l = ps;
  int c0 = lane * 2;
  ushort2 hv = *reinterpret_cast<const ushort2*>(hp + (size_t)n * 128 + c0);
  float a0 = ps * bf2f(hv.x), a1 = ps * bf2f(hv.y);
  for (int j = beg; j < end; ++j){
    int s = csr[j];
    float p = __expf(lrelu(al[s] + ald) - m);
    ushort2 v = *reinterpret_cast<const ushort2*>(hp + (size_t)s * 128 + c0);
    a0 = fmaf(p, bf2f(v.x), a0);
    a1 = fmaf(p, bf2f(v.y), a1);
    l += p;
  }
  float inv = 1.f / l;
  pairv[w * 128 + c0]     = a0 * inv + bias[c0];
  pairv[w * 128 + c0 + 1] = a1 * inv + bias[c0 + 1];
  __syncthreads();
  float acc1 = mb1[t];
  for (int k = 0; k < 256; ++k) acc1 = fmaf(pairv[k], mw1[k * 128 + t], acc1);
  z1[t] = fmaxf(acc1, 0.f);
  __syncthreads();
  if (t < 64){
    float a2 = mb2[t];
    for (int k = 0; k < 128; ++k) a2 = fmaf(z1[k], mw2[k * 64 + t], a2);
    z2[t] = fmaxf(a2, 0.f);
  }
  __syncthreads();
  if (t < 64){
    float p = z2[t] * mw3[t];
    #pragma unroll
    for (int off = 32; off >= 1; off >>= 1) p += __shfl_xor(p, off);
    if (t == 0) out[r] = 1.f / (1.f + __expf(-(p + mb3[0])));
  }
  (void)B;
}

// ---------------- launch ----------------
extern "C" void kernel_launch(void* const* d_in, const int* in_sizes, int n_in,
                              void* d_out, int out_size, void* d_ws, size_t ws_size,
                              hipStream_t stream){
  const float* x   = (const float*)d_in[0];
  const int*   ei  = (const int*)  d_in[1];
  const int*   liq = (const int*)  d_in[2];
  const int*   ing = (const int*)  d_in[3];
  const float* W1  = (const float*)d_in[4];
  const float* as1 = (const float*)d_in[5];
  const float* ad1 = (const float*)d_in[6];
  const float* b1  = (const float*)d_in[7];
  const float* W2  = (const float*)d_in[8];
  const float* as2 = (const float*)d_in[9];
  const float* ad2 = (const float*)d_in[10];
  const float* b2  = (const float*)d_in[11];
  const float* W3  = (const float*)d_in[12];
  const float* as3 = (const float*)d_in[13];
  const float* ad3 = (const float*)d_in[14];
  const float* b3  = (const float*)d_in[15];
  const float* mw1 = (const float*)d_in[16];
  const float* mb1 = (const float*)d_in[17];
  const float* mw2 = (const float*)d_in[18];
  const float* mb2 = (const float*)d_in[19];
  const float* mw3 = (const float*)d_in[20];
  const float* mb3 = (const float*)d_in[21];
  float* out = (float*)d_out;

  const int N = in_sizes[0] / 64;      // 25000
  const int E = in_sizes[1] / 2;       // 200000
  const int B = in_sizes[2];           // 4096
  const int* srcp = ei;
  const int* dstp = ei + E;

  char* w = (char*)d_ws;
  auto alloc = [&](size_t bytes) -> char* {
    char* p = w;
    w += (bytes + 255) & ~(size_t)255;
    return p;
  };
  unsigned short* P    = (unsigned short*)alloc((size_t)N * 1024 * 2);  // Php / G / P3
  unsigned short* Hb   = (unsigned short*)alloc((size_t)N * 1024 * 2);
  unsigned short* xb   = (unsigned short*)alloc((size_t)N * 64 * 2);
  unsigned short* Wt1  = (unsigned short*)alloc((size_t)1024 * 64 * 2);
  unsigned short* Wt2  = (unsigned short*)alloc((size_t)1024 * 1024 * 2);
  unsigned short* Wt3  = (unsigned short*)alloc((size_t)128 * 1024 * 2);
  float* ALS  = (float*)alloc((size_t)N * 8 * 4);
  float* ALD  = (float*)alloc((size_t)N * 8 * 4);
  float* alpha= (float*)alloc((size_t)E * 8 * 4);
  float* alps = (float*)alloc((size_t)N * 8 * 4);
  float* invl = (float*)alloc((size_t)N * 8 * 4);
  float* ws1  = (float*)alloc((size_t)64 * 16 * 4);
  int*   row  = (int*)  alloc((size_t)(N + 1) * 4);
  int*   cntcur = (int*)alloc((size_t)2 * N * 4);
  int*   cnt  = cntcur;
  int*   cur  = cntcur + N;
  int*   aux  = (int*)  alloc((size_t)256 * 4);
  int*   csr  = (int*)  alloc((size_t)E * 4);
  unsigned short* G = P;   // alias: G[N,512] lives in P until layer-2 GEMM overwrites
  (void)ws_size; (void)n_in; (void)out_size;

  // fused conversions + layer-1 fold (one launch)
  int nx = N * 64;
  int nxb = (nx + 2047) / 2048;
  k_prep<<<nxb + 64 + 1024 + 128 + 64, 256, 0, stream>>>(
      x, xb, nx, nxb, W1, Wt1, W2, Wt2, W3, Wt3, as1, ad1, ws1);

  // CSR build
  hipMemsetAsync(cntcur, 0, (size_t)2 * N * 4, stream);
  int eb = (E + 255) / 256;
  int nb = (N + 255) / 256;
  k_count<<<eb, 256, 0, stream>>>(dstp, cnt, E);
  k_blockscan<<<nb, 256, 0, stream>>>(cnt, row, aux, N);
  k_addoff<<<nb, 256, 0, stream>>>(aux, row, N);
  k_scatter<<<eb, 256, 0, stream>>>(srcp, dstp, row, cur, csr, E);

  const int mt  = (N + 127) / 128;     // 196
  const int mt2 = (N + 255) / 256;     // 98
  const int smb8 = (N * 8 + 255) / 256;

  // ---- layer 1: logits from x, softmax precompute, weighted gather, project ----
  k_logits1<<<(N + 31) / 32, 256, 0, stream>>>(xb, ws1, ALS, ALD, N);
  k_sm<8,0><<<smb8, 256, 0, stream>>>(ALS, ALD, row, csr, alpha, alps, invl, N, E);
  k_gat_x<<<(N + 3) / 4, 256, 0, stream>>>(xb, alpha, alps, invl, row, csr, G, N);
  k_gemm_g<<<8 * mt, 256, 0, stream>>>(G, Wt1, b1, Hb, N);

  // ---- layer 2: 3-barrier pipelined GEMM (head-major out) + transposed softmax + XCD gather ----
  k_gemm256p8<<<4 * mt2, 512, 0, stream>>>(Hb, Wt2, P, as2, ad2, ALS, ALD, N, 1024, 1024, 4);
  k_sm<8,1><<<smb8, 256, 0, stream>>>(ALS, ALD, row, csr, alpha, alps, invl, N, E);
  k_gat2h<<<8 * ((N + 15) / 16), 256, 0, stream>>>(P, alpha, alps, invl, row, csr, b2, Hb, N, E);

  // ---- layer 3: Hb @ W3 (1 head) + fused gather/MLP for used nodes only ----
  k_gemm_fused<1><<<1 * mt, 256, 0, stream>>>(Hb, Wt3, P, as3, ad3, ALS, ALD, N, 128, 1024, 1);
  k_pair<<<B, 128, 0, stream>>>(P, ALS, ALD, row, csr, b3, liq, ing,
                                mw1, mb1, mw2, mb2, mw3, mb3, out, B);
}

// Round 16
// 302.935 us; speedup vs baseline: 1.0094x; 1.0094x over previous
//
#include <hip/hip_runtime.h>
#include <math.h>

#define NEG_SLOPE 0.2f

typedef short short8 __attribute__((ext_vector_type(8)));
typedef float f32x4 __attribute__((ext_vector_type(4)));

__device__ __forceinline__ float lrelu(float x){ return x > 0.f ? x : NEG_SLOPE * x; }

__device__ __forceinline__ unsigned short f2bf(float f){
  union { float f; unsigned u; } v; v.f = f;
  unsigned r = v.u + 0x7fff + ((v.u >> 16) & 1);  // RNE
  return (unsigned short)(r >> 16);
}
__device__ __forceinline__ float bf2f(unsigned short u){
  union { unsigned u; float f; } v; v.u = ((unsigned)u) << 16; return v.f;
}

__device__ __forceinline__ void gld16(const unsigned short* g, unsigned short* l){
  __builtin_amdgcn_global_load_lds(
      (const __attribute__((address_space(1))) unsigned int*)g,
      (__attribute__((address_space(3))) unsigned int*)l, 16, 0, 0);
}

#define MFMA_BF16 __builtin_amdgcn_mfma_f32_16x16x32_bf16

// ---------------- CSR build (dst-indexed) ----------------
__global__ void k_count(const int* __restrict__ dst, int* __restrict__ cnt, int E){
  int e = blockIdx.x*blockDim.x + threadIdx.x;
  if (e < E) atomicAdd(&cnt[dst[e]], 1);
}

__global__ void k_blockscan(const int* __restrict__ cnt, int* __restrict__ row,
                            int* __restrict__ aux, int n){
  __shared__ int buf[256];
  int t = threadIdx.x;
  int base = blockIdx.x * 256;
  int v = (base + t < n) ? cnt[base + t] : 0;
  buf[t] = v;
  __syncthreads();
  #pragma unroll
  for (int off = 1; off < 256; off <<= 1){
    int u = (t >= off) ? buf[t - off] : 0;
    __syncthreads();
    buf[t] += u;
    __syncthreads();
  }
  if (base + t < n) row[base + t + 1] = buf[t];
  if (t == 255) aux[blockIdx.x] = buf[255];
  if (blockIdx.x == 0 && t == 0) row[0] = 0;
}

__global__ void k_addoff(const int* __restrict__ aux, int* __restrict__ row, int n){
  __shared__ int sbuf[256];
  int b = blockIdx.x, t = threadIdx.x;
  sbuf[t] = (t < b) ? aux[t] : 0;
  __syncthreads();
  #pragma unroll
  for (int off = 128; off >= 1; off >>= 1){
    if (t < off) sbuf[t] += sbuf[t + off];
    __syncthreads();
  }
  int i = b * 256 + t;
  if (i < n) row[i + 1] += sbuf[0];
}

__global__ void k_scatter(const int* __restrict__ src, const int* __restrict__ dst,
                          const int* __restrict__ row, int* __restrict__ cur,
                          int* __restrict__ csr, int E){
  int e = blockIdx.x*blockDim.x + threadIdx.x;
  if (e < E){
    int d = dst[e];
    int p = atomicAdd(&cur[d], 1);
    csr[row[d] + p] = src[e];
  }
}

// ------- fused prep: x->bf16 + 3 weight transposes + layer-1 attention fold -------
__global__ void k_prep(const float* __restrict__ x, unsigned short* __restrict__ xb, int nx, int nxb,
                       const float* __restrict__ W1, unsigned short* __restrict__ Wt1,
                       const float* __restrict__ W2, unsigned short* __restrict__ Wt2,
                       const float* __restrict__ W3, unsigned short* __restrict__ Wt3,
                       const float* __restrict__ a_s1, const float* __restrict__ a_d1,
                       float* __restrict__ ws1){
  __shared__ float tile[32][33];
  int b = blockIdx.x, t = threadIdx.x;
  if (b < nxb){
    int i0 = b * 2048 + t * 8;
    if (i0 + 8 <= nx){
      float4 f0 = *reinterpret_cast<const float4*>(x + i0);
      float4 f1 = *reinterpret_cast<const float4*>(x + i0 + 4);
      short8 o;
      o[0]=f2bf(f0.x); o[1]=f2bf(f0.y); o[2]=f2bf(f0.z); o[3]=f2bf(f0.w);
      o[4]=f2bf(f1.x); o[5]=f2bf(f1.y); o[6]=f2bf(f1.z); o[7]=f2bf(f1.w);
      *reinterpret_cast<short8*>(xb + i0) = o;
    } else {
      for (int k = 0; k < 8 && i0 + k < nx; ++k) xb[i0 + k] = f2bf(x[i0 + k]);
    }
    return;
  }
  int bp = b - nxb;
  if (bp >= 64 + 1024 + 128){
    int k = bp - (64 + 1024 + 128);
    int h = t >> 5, lq = t & 31;
    float4 wv = *reinterpret_cast<const float4*>(&W1[(size_t)k * 1024 + h * 128 + lq * 4]);
    float4 sv = *reinterpret_cast<const float4*>(&a_s1[h * 128 + lq * 4]);
    float4 dv = *reinterpret_cast<const float4*>(&a_d1[h * 128 + lq * 4]);
    float ps = wv.x*sv.x + wv.y*sv.y + wv.z*sv.z + wv.w*sv.w;
    float pd = wv.x*dv.x + wv.y*dv.y + wv.z*dv.z + wv.w*dv.w;
    #pragma unroll
    for (int off = 16; off >= 1; off >>= 1){
      ps += __shfl_xor(ps, off);
      pd += __shfl_xor(pd, off);
    }
    if (lq == 0){ ws1[k * 16 + h] = ps; ws1[k * 16 + 8 + h] = pd; }
    return;
  }
  const float* W; unsigned short* Wt; int K, N, ti;
  if (bp < 64)            { W = W1; Wt = Wt1; K = 64;   N = 1024; ti = bp;
                            int kb = (ti & 1) * 32, nb = (ti >> 1) * 32;
                            int tx = t & 31, ty = t >> 5;
                            #pragma unroll
                            for (int i = ty; i < 32; i += 8) tile[i][tx] = W[(size_t)(kb+i)*N + nb+tx];
                            __syncthreads();
                            #pragma unroll
                            for (int i = ty; i < 32; i += 8) Wt[(size_t)(nb+i)*K + kb+tx] = f2bf(tile[tx][i]);
                            return; }
  if (bp < 64 + 1024)     { W = W2; Wt = Wt2; K = 1024; N = 1024; ti = bp - 64; }
  else                    { W = W3; Wt = Wt3; K = 1024; N = 128;  ti = bp - 64 - 1024; }
  int kb = (ti & 31) * 32, nb = (ti >> 5) * 32;
  int tx = t & 31, ty = t >> 5;
  #pragma unroll
  for (int i = ty; i < 32; i += 8) tile[i][tx] = W[(size_t)(kb+i)*N + nb+tx];
  __syncthreads();
  #pragma unroll
  for (int i = ty; i < 32; i += 8) Wt[(size_t)(nb+i)*K + kb+tx] = f2bf(tile[tx][i]);
}

// ---------------- layer-1 logits ----------------
__global__ void k_logits1(const unsigned short* __restrict__ xb, const float* __restrict__ ws,
                          float* __restrict__ ALS, float* __restrict__ ALD, int N){
  __shared__ unsigned short lx[32 * 64];
  __shared__ float lw[64 * 16];
  int t = threadIdx.x;
  int n0 = blockIdx.x * 32;
  int r = t >> 3, c = (t & 7) * 8;
  if (n0 + r < N)
    *reinterpret_cast<short8*>(&lx[r * 64 + c]) =
      *reinterpret_cast<const short8*>(&xb[(size_t)(n0 + r) * 64 + c]);
  else {
    short8 z = {0,0,0,0,0,0,0,0};
    *reinterpret_cast<short8*>(&lx[r * 64 + c]) = z;
  }
  *reinterpret_cast<float4*>(&lw[t * 4]) = *reinterpret_cast<const float4*>(&ws[t * 4]);
  __syncthreads();
  int nl = t >> 3, h = t & 7;
  if (n0 + nl >= N) return;
  float s = 0.f, d = 0.f;
  #pragma unroll 8
  for (int k = 0; k < 64; ++k){
    float xv = bf2f(lx[nl * 64 + k]);
    s = fmaf(xv, lw[k * 16 + h], s);
    d = fmaf(xv, lw[k * 16 + 8 + h], d);
  }
  ALS[(size_t)(n0 + nl) * 8 + h] = s;
  ALD[(size_t)(n0 + nl) * 8 + h] = d;
}

// ------- softmax precompute; TR=0: alpha[j*H+h], TR=1: alpha[h*E+j] (head-major) -------
template<int HEADS, int TR>
__global__ void k_sm(const float* __restrict__ ALS, const float* __restrict__ ALD,
                     const int* __restrict__ row, const int* __restrict__ csr,
                     float* __restrict__ alpha, float* __restrict__ alps,
                     float* __restrict__ invl, int N, int E){
  int idx = blockIdx.x * blockDim.x + threadIdx.x;
  int n = idx / HEADS, h = idx - n * HEADS;
  if (n >= N) return;
  float ald = ALD[(size_t)n * HEADS + h];
  float es = lrelu(ALS[(size_t)n * HEADS + h] + ald);   // self-loop logit
  float m = es;
  int beg = row[n], end = row[n + 1];
  for (int j = beg; j < end; ++j)
    m = fmaxf(m, lrelu(ALS[(size_t)csr[j] * HEADS + h] + ald));
  float ps = __expf(es - m);
  float l = ps;
  for (int j = beg; j < end; ++j){
    float p = __expf(lrelu(ALS[(size_t)csr[j] * HEADS + h] + ald) - m);
    if (TR) alpha[(size_t)h * E + j] = p;
    else    alpha[(size_t)j * HEADS + h] = p;
    l += p;
  }
  alps[(size_t)n * HEADS + h] = ps;
  invl[(size_t)n * HEADS + h] = 1.f / l;
}

// ---------------- layer-1 gather on x: pure weighted sum ----------------
__global__ void k_gat_x(const unsigned short* __restrict__ xb, const float* __restrict__ alpha,
                        const float* __restrict__ alps, const float* __restrict__ invl,
                        const int* __restrict__ row, const int* __restrict__ csr,
                        unsigned short* __restrict__ G, int N){
  int t = threadIdx.x;
  int n = blockIdx.x * 4 + (t >> 6);
  if (n >= N) return;
  int lane = t & 63;
  float xv = bf2f(xb[(size_t)n * 64 + lane]);
  float4 s0 = *reinterpret_cast<const float4*>(&alps[(size_t)n * 8]);
  float4 s1 = *reinterpret_cast<const float4*>(&alps[(size_t)n * 8 + 4]);
  float acc[8] = {s0.x*xv, s0.y*xv, s0.z*xv, s0.w*xv, s1.x*xv, s1.y*xv, s1.z*xv, s1.w*xv};
  int beg = row[n], end = row[n + 1];
  for (int j = beg; j < end; ++j){
    int s = csr[j];
    float xs = bf2f(xb[(size_t)s * 64 + lane]);
    float4 a0 = *reinterpret_cast<const float4*>(&alpha[(size_t)j * 8]);
    float4 a1 = *reinterpret_cast<const float4*>(&alpha[(size_t)j * 8 + 4]);
    acc[0] = fmaf(a0.x, xs, acc[0]);
    acc[1] = fmaf(a0.y, xs, acc[1]);
    acc[2] = fmaf(a0.z, xs, acc[2]);
    acc[3] = fmaf(a0.w, xs, acc[3]);
    acc[4] = fmaf(a1.x, xs, acc[4]);
    acc[5] = fmaf(a1.y, xs, acc[5]);
    acc[6] = fmaf(a1.z, xs, acc[6]);
    acc[7] = fmaf(a1.w, xs, acc[7]);
  }
  float4 i0 = *reinterpret_cast<const float4*>(&invl[(size_t)n * 8]);
  float4 i1 = *reinterpret_cast<const float4*>(&invl[(size_t)n * 8 + 4]);
  float iv[8] = {i0.x, i0.y, i0.z, i0.w, i1.x, i1.y, i1.z, i1.w};
  #pragma unroll
  for (int h = 0; h < 8; ++h)
    G[(size_t)n * 512 + h * 64 + lane] = f2bf(acc[h] * iv[h]);
}

// ---------------- layer-1 GEMM (K=64 per head) ----------------
__global__ __launch_bounds__(256) void k_gemm_g(
    const unsigned short* __restrict__ G,    // [M,512] bf16
    const unsigned short* __restrict__ Bt,   // Wt1 [1024,64] bf16
    const float* __restrict__ bias,          // [1024]
    unsigned short* __restrict__ C,          // [M,1024] bf16
    int M){
  __shared__ unsigned short As[128 * 32];
  __shared__ unsigned short Bs[128 * 32];
  const int nwg = gridDim.x;
  int bid = blockIdx.x;
  int swz = ((nwg & 7) == 0) ? ((bid & 7) * (nwg >> 3) + (bid >> 3)) : bid;
  const int head = swz % 8, byi = swz / 8;
  const int bm = byi * 128, bn = head * 128;
  const int tid  = threadIdx.x;
  const int lane = tid & 63, wave = tid >> 6;
  const int wr = wave >> 1, wc = wave & 1;
  const int lr = lane & 15, lk = lane >> 4;
  const int srow = wave * 16 + (lane >> 2);
  const int skc  = (lane & 3) * 8;
  int ar0 = bm + srow;      if (ar0 >= M) ar0 = M - 1;
  int ar1 = bm + srow + 64; if (ar1 >= M) ar1 = M - 1;
  const unsigned short* ga0 = G + (size_t)ar0 * 512 + head * 64 + skc;
  const unsigned short* ga1 = G + (size_t)ar1 * 512 + head * 64 + skc;
  const unsigned short* gb0 = Bt + (size_t)(bn + srow) * 64 + skc;
  const unsigned short* gb1 = Bt + (size_t)(bn + srow + 64) * 64 + skc;
  f32x4 acc[4][4] = {};
  #pragma unroll
  for (int k0 = 0; k0 < 64; k0 += 32){
    gld16(ga0 + k0, &As[(size_t)wave * 512]);
    gld16(ga1 + k0, &As[(size_t)(wave + 4) * 512]);
    gld16(gb0 + k0, &Bs[(size_t)wave * 512]);
    gld16(gb1 + k0, &Bs[(size_t)(wave + 4) * 512]);
    __syncthreads();
    short8 af[4], bg[4];
    #pragma unroll
    for (int m = 0; m < 4; ++m)
      af[m] = *reinterpret_cast<const short8*>(&As[(wr * 64 + m * 16 + lr) * 32 + lk * 8]);
    #pragma unroll
    for (int n = 0; n < 4; ++n)
      bg[n] = *reinterpret_cast<const short8*>(&Bs[(wc * 64 + n * 16 + lr) * 32 + lk * 8]);
    #pragma unroll
    for (int m = 0; m < 4; ++m)
      #pragma unroll
      for (int n = 0; n < 4; ++n)
        acc[m][n] = MFMA_BF16(af[m], bg[n], acc[m][n], 0, 0, 0);
    __syncthreads();
  }
  float bv[4];
  #pragma unroll
  for (int n = 0; n < 4; ++n) bv[n] = bias[bn + wc * 64 + n * 16 + lr];
  #pragma unroll
  for (int m = 0; m < 4; ++m){
    #pragma unroll
    for (int j = 0; j < 4; ++j){
      int rowi = bm + wr * 64 + m * 16 + lk * 4 + j;
      if (rowi < M){
        #pragma unroll
        for (int n = 0; n < 4; ++n)
          C[(size_t)rowi * 1024 + bn + wc * 64 + n * 16 + lr] = f2bf(fmaxf(acc[m][n][j] + bv[n], 0.f));
      }
    }
  }
}

// ---------------- m97-style GEMM + fused logits (layer 3) ----------------
template<int HEADS>
__global__ __launch_bounds__(256) void k_gemm_fused(
    const unsigned short* __restrict__ A, const unsigned short* __restrict__ Bt,
    unsigned short* __restrict__ C,
    const float* __restrict__ a_s, const float* __restrict__ a_d,
    float* __restrict__ ALS, float* __restrict__ ALD,
    int M, int N, int K, int gxc){
  __shared__ unsigned short SMEM[2 * 128 * 32];
  unsigned short* As = SMEM;
  unsigned short* Bs = SMEM + 128 * 32;
  const int nwg = gridDim.x;
  int bid = blockIdx.x;
  int swz = ((nwg & 7) == 0) ? ((bid & 7) * (nwg >> 3) + (bid >> 3)) : bid;
  const int bxi = swz % gxc, byi = swz / gxc;
  const int bm = byi * 128, bn = bxi * 128;
  const int head = bxi;
  const int tid  = threadIdx.x;
  const int lane = tid & 63, wave = tid >> 6;
  const int wr = wave >> 1, wc = wave & 1;
  const int lr = lane & 15, lk = lane >> 4;
  const int srow = wave * 16 + (lane >> 2);
  const int skc  = (lane & 3) * 8;
  int ar0 = bm + srow;      if (ar0 >= M) ar0 = M - 1;
  int ar1 = bm + srow + 64; if (ar1 >= M) ar1 = M - 1;
  const unsigned short* ga0 = A  + (size_t)ar0 * K + skc;
  const unsigned short* ga1 = A  + (size_t)ar1 * K + skc;
  const unsigned short* gb0 = Bt + (size_t)(bn + srow) * K + skc;
  const unsigned short* gb1 = Bt + (size_t)(bn + srow + 64) * K + skc;
  f32x4 acc[4][4] = {};
  for (int k0 = 0; k0 < K; k0 += 32){
    gld16(ga0 + k0, &As[(size_t)wave * 512]);
    gld16(ga1 + k0, &As[(size_t)(wave + 4) * 512]);
    gld16(gb0 + k0, &Bs[(size_t)wave * 512]);
    gld16(gb1 + k0, &Bs[(size_t)(wave + 4) * 512]);
    __syncthreads();
    short8 af[4], bg[4];
    #pragma unroll
    for (int m = 0; m < 4; ++m)
      af[m] = *reinterpret_cast<const short8*>(&As[(wr * 64 + m * 16 + lr) * 32 + lk * 8]);
    #pragma unroll
    for (int n = 0; n < 4; ++n)
      bg[n] = *reinterpret_cast<const short8*>(&Bs[(wc * 64 + n * 16 + lr) * 32 + lk * 8]);
    #pragma unroll
    for (int m = 0; m < 4; ++m)
      #pragma unroll
      for (int n = 0; n < 4; ++n)
        acc[m][n] = MFMA_BF16(af[m], bg[n], acc[m][n], 0, 0, 0);
    __syncthreads();
  }
  #pragma unroll
  for (int m = 0; m < 4; ++m){
    #pragma unroll
    for (int j = 0; j < 4; ++j){
      int rowi = bm + wr * 64 + m * 16 + lk * 4 + j;
      if (rowi < M){
        #pragma unroll
        for (int n = 0; n < 4; ++n)
          C[(size_t)rowi * N + bn + wc * 64 + n * 16 + lr] = f2bf(acc[m][n][j]);
      }
    }
  }
  float as4[4], ad4[4];
  #pragma unroll
  for (int n = 0; n < 4; ++n){
    as4[n] = a_s[head * 128 + wc * 64 + n * 16 + lr];
    ad4[n] = a_d[head * 128 + wc * 64 + n * 16 + lr];
  }
  float* red = (float*)SMEM;
  #pragma unroll
  for (int m = 0; m < 4; ++m){
    #pragma unroll
    for (int j = 0; j < 4; ++j){
      float ps = 0.f;
      #pragma unroll
      for (int n = 0; n < 4; ++n) ps = fmaf(acc[m][n][j], as4[n], ps);
      red[(wr * 64 + m * 16 + lk * 4 + j) * 32 + wc * 16 + lr] = ps;
    }
  }
  __syncthreads();
  if (tid < 128){
    float s = 0.f;
    #pragma unroll
    for (int i = 0; i < 32; ++i) s += red[tid * 32 + ((i + tid) & 31)];
    int gr = bm + tid;
    if (gr < M) ALS[(size_t)gr * HEADS + head] = s;
  }
  __syncthreads();
  #pragma unroll
  for (int m = 0; m < 4; ++m){
    #pragma unroll
    for (int j = 0; j < 4; ++j){
      float pd = 0.f;
      #pragma unroll
      for (int n = 0; n < 4; ++n) pd = fmaf(acc[m][n][j], ad4[n], pd);
      red[(wr * 64 + m * 16 + lk * 4 + j) * 32 + wc * 16 + lr] = pd;
    }
  }
  __syncthreads();
  if (tid < 128){
    float s = 0.f;
    #pragma unroll
    for (int i = 0; i < 32; ++i) s += red[tid * 32 + ((i + tid) & 31)];
    int gr = bm + tid;
    if (gr < M) ALD[(size_t)gr * HEADS + head] = s;
  }
}

// ---- 256x256 bf16 GEMM + fused logits (layer 2); SINGLE-buffer 64 KiB -> 2 blocks/CU ----
// Per tile: 12 ds_reads -> barrier -> lgkmcnt(0) -> Q1 MFMA -> stage kt+1 (8 gld16) ->
// Q2-Q4 MFMA -> vmcnt(0) -> barrier. Drain hidden by co-resident block (m97/m114
// wave-level overlap). C out HEAD-MAJOR.
__global__ __launch_bounds__(512, 2) void k_gemm256s(
    const unsigned short* __restrict__ A,   // [M,K] bf16
    const unsigned short* __restrict__ Bt,  // [N,K] bf16
    unsigned short* __restrict__ Php,       // [8][M][128] bf16 (head-major)
    const float* __restrict__ a_s, const float* __restrict__ a_d,
    float* __restrict__ ALS, float* __restrict__ ALD,   // [M,8]
    int M, int N, int K, int gxc){
  __shared__ unsigned short smem[32768];   // A @0 (256x64), B @16384 (256x64) = 64 KiB
  const int nwg = gridDim.x;
  int bid = blockIdx.x;
  int swz = ((nwg & 7) == 0) ? ((bid & 7) * (nwg >> 3) + (bid >> 3)) : bid;
  const int bxi = swz % gxc, byi = swz / gxc;
  const int bm = byi * 256, bn = bxi * 256;
  const int tid = threadIdx.x;
  const int lane = tid & 63, wave = tid >> 6;
  const int wr = wave >> 2, wc = wave & 3;     // 2 x 4
  const int lr = lane & 15, lk = lane >> 4;
  const int sr = tid >> 3;
  const int scol = ((tid & 7) << 3) ^ ((sr & 7) << 3);
  unsigned offA[4], offB[4];
  #pragma unroll
  for (int u = 0; u < 4; ++u){
    int r = bm + u * 64 + sr; if (r >= M) r = M - 1;
    offA[u] = (unsigned)r * (unsigned)K + scol;
    offB[u] = (unsigned)(bn + u * 64 + sr) * (unsigned)K + scol;
  }
  const int wdst = wave * 512;
  const int NKT = K >> 6;

  #define STA(T,u) gld16(A  + (size_t)offA[u] + (size_t)(T)*64, &smem[(u)*4096 + wdst])
  #define STB(T,u) gld16(Bt + (size_t)offB[u] + (size_t)(T)*64, &smem[16384 + (u)*4096 + wdst])

  // prologue: stage tile 0
  #pragma unroll
  for (int u = 0; u < 4; ++u) STA(0, u);
  #pragma unroll
  for (int u = 0; u < 4; ++u) STB(0, u);
  asm volatile("s_waitcnt vmcnt(0)" ::: "memory");
  __builtin_amdgcn_s_barrier();

  f32x4 acc[8][4] = {};
  short8 afA[4][2], afB[4][2], bg[4][2];

  #define RD_AF(dst, moff) \
    _Pragma("unroll") \
    for (int m = 0; m < 4; ++m){ \
      int row = wr * 128 + (m + (moff)) * 16 + lr; \
      int rb = row * 64, sw = (row & 7) << 3; \
      dst[m][0] = *reinterpret_cast<const short8*>(&smem[rb + ((lk * 8) ^ sw)]); \
      dst[m][1] = *reinterpret_cast<const short8*>(&smem[rb + ((32 + lk * 8) ^ sw)]); \
    }
  #define RD_BG() \
    _Pragma("unroll") \
    for (int n = 0; n < 4; ++n){ \
      int row = wc * 64 + n * 16 + lr; \
      int rb = 16384 + row * 64, sw = (row & 7) << 3; \
      bg[n][0] = *reinterpret_cast<const short8*>(&smem[rb + ((lk * 8) ^ sw)]); \
      bg[n][1] = *reinterpret_cast<const short8*>(&smem[rb + ((32 + lk * 8) ^ sw)]); \
    }
  #define QUADX(src, mb, nb) \
    _Pragma("unroll") \
    for (int m = 0; m < 4; ++m) \
      _Pragma("unroll") \
      for (int n = 0; n < 2; ++n){ \
        acc[(mb)+m][(nb)+n] = MFMA_BF16(src[m][0], bg[(nb)+n][0], acc[(mb)+m][(nb)+n], 0, 0, 0); \
        acc[(mb)+m][(nb)+n] = MFMA_BF16(src[m][1], bg[(nb)+n][1], acc[(mb)+m][(nb)+n], 0, 0, 0); \
      }

  for (int kt = 0; kt < NKT; ++kt){
    // read everything of tile kt into registers
    RD_AF(afA, 0);
    RD_AF(afB, 4);
    RD_BG();
    __builtin_amdgcn_s_barrier();                       // all waves issued reads
    asm volatile("s_waitcnt lgkmcnt(0)" ::: "memory");  // own reads complete
    __builtin_amdgcn_sched_barrier(0);
    // Q1 (buys time so every wave's reads are complete before staging lands)
    __builtin_amdgcn_s_setprio(1);
    QUADX(afA, 0, 0);
    __builtin_amdgcn_s_setprio(0);
    // stage tile kt+1 over the same buffer (DMA lands >=500cy out; reads done ~120cy)
    if (kt + 1 < NKT){
      STA(kt + 1, 0); STA(kt + 1, 1); STA(kt + 1, 2); STA(kt + 1, 3);
      STB(kt + 1, 0); STB(kt + 1, 1); STB(kt + 1, 2); STB(kt + 1, 3);
    }
    __builtin_amdgcn_s_setprio(1);
    QUADX(afA, 0, 2);
    QUADX(afB, 4, 0);
    QUADX(afB, 4, 2);
    __builtin_amdgcn_s_setprio(0);
    asm volatile("s_waitcnt vmcnt(0)" ::: "memory");    // tile kt+1 landed
    __builtin_amdgcn_s_barrier();
  }

  // ---- C store (bf16, head-major) ----
  const int hloc = wc >> 1;
  const int head = bxi * 2 + hloc;
  const int cc = (wc & 1) * 64;
  #pragma unroll
  for (int m = 0; m < 8; ++m){
    #pragma unroll
    for (int j = 0; j < 4; ++j){
      int row = bm + wr * 128 + m * 16 + lk * 4 + j;
      if (row < M){
        #pragma unroll
        for (int n = 0; n < 4; ++n)
          Php[((size_t)head * M + row) * 128 + cc + n * 16 + lr] = f2bf(acc[m][n][j]);
      }
    }
  }
  // ---- fused logits (2 heads per block) ----
  float as4[4], ad4[4];
  #pragma unroll
  for (int n = 0; n < 4; ++n){
    as4[n] = a_s[head * 128 + cc + n * 16 + lr];
    ad4[n] = a_d[head * 128 + cc + n * 16 + lr];
  }
  float2* red = (float2*)smem;      // [256][32] float2 = 64 KB
  __syncthreads();
  #pragma unroll
  for (int hh = 0; hh < 2; ++hh){
    if (hloc == hh){
      #pragma unroll
      for (int m = 0; m < 8; ++m){
        #pragma unroll
        for (int j = 0; j < 4; ++j){
          float ps = 0.f, pd = 0.f;
          #pragma unroll
          for (int n = 0; n < 4; ++n){
            ps = fmaf(acc[m][n][j], as4[n], ps);
            pd = fmaf(acc[m][n][j], ad4[n], pd);
          }
          red[(wr * 128 + m * 16 + lk * 4 + j) * 32 + (wc & 1) * 16 + lr] = make_float2(ps, pd);
        }
      }
    }
    __syncthreads();
    if (tid < 256){
      float ss = 0.f, sd = 0.f;
      #pragma unroll
      for (int i = 0; i < 32; ++i){
        float2 v = red[tid * 32 + ((i + tid) & 31)];
        ss += v.x; sd += v.y;
      }
      int gr = bm + tid;
      if (gr < M){
        ALS[(size_t)gr * 8 + bxi * 2 + hh] = ss;
        ALD[(size_t)gr * 8 + bxi * 2 + hh] = sd;
      }
    }
    __syncthreads();
  }
  #undef STA
  #undef STB
  #undef RD_AF
  #undef RD_BG
  #undef QUADX
}

// --- layer-2 gather, head-major: one head per block; head = bid&7 (XCD affinity) ---
__global__ void k_gat2h(const unsigned short* __restrict__ Php,  // [8][N][128] bf16
                        const float* __restrict__ alpha,         // [8][E] (head-major)
                        const float* __restrict__ alps, const float* __restrict__ invl, // [N,8]
                        const int* __restrict__ row, const int* __restrict__ csr,
                        const float* __restrict__ bias, unsigned short* __restrict__ outv,
                        int N, int E){
  int h = blockIdx.x & 7;
  int nb = blockIdx.x >> 3;
  int t = threadIdx.x;            // 256 = 16 nodes x 16 threads
  int n = nb * 16 + (t >> 4);
  if (n >= N) return;
  int c0 = (t & 15) * 8;
  const unsigned short* hb = Php + (size_t)h * N * 128;
  const float* alp = alpha + (size_t)h * E;
  float sp = alps[(size_t)n * 8 + h];
  short8 hv8 = *reinterpret_cast<const short8*>(hb + (size_t)n * 128 + c0);
  float accA[8], accB[8] = {};
  #pragma unroll
  for (int v = 0; v < 8; ++v) accA[v] = sp * bf2f((unsigned short)hv8[v]);
  int beg = row[n], end = row[n + 1];
  int j = beg;
  for (; j + 1 < end; j += 2){
    int s0 = csr[j], s1 = csr[j + 1];
    float p0 = alp[j], p1 = alp[j + 1];
    short8 v0 = *reinterpret_cast<const short8*>(hb + (size_t)s0 * 128 + c0);
    short8 v1 = *reinterpret_cast<const short8*>(hb + (size_t)s1 * 128 + c0);
    #pragma unroll
    for (int v = 0; v < 8; ++v){
      accA[v] = fmaf(p0, bf2f((unsigned short)v0[v]), accA[v]);
      accB[v] = fmaf(p1, bf2f((unsigned short)v1[v]), accB[v]);
    }
  }
  if (j < end){
    int s0 = csr[j];
    float p0 = alp[j];
    short8 v0 = *reinterpret_cast<const short8*>(hb + (size_t)s0 * 128 + c0);
    #pragma unroll
    for (int v = 0; v < 8; ++v) accA[v] = fmaf(p0, bf2f((unsigned short)v0[v]), accA[v]);
  }
  float inv = invl[(size_t)n * 8 + h];
  size_t ob = ((size_t)n * 8 + h) * 128 + c0;
  #pragma unroll
  for (int v = 0; v < 8; ++v){
    float o = fmaxf((accA[v] + accB[v]) * inv + bias[h * 128 + c0 + v], 0.f);
    outv[ob + v] = f2bf(o);
  }
}

// ------- fused layer-3 gather (inline softmax, used nodes only) + MLP scorer -------
__global__ void k_pair(const unsigned short* __restrict__ hp,   // P3 [N,128] bf16
                       const float* __restrict__ al, const float* __restrict__ aldv,  // [N]
                       const int* __restrict__ row, const int* __restrict__ csr,
                       const float* __restrict__ bias,          // b3 [128]
                       const int* __restrict__ liq, const int* __restrict__ ing,
                       const float* __restrict__ mw1, const float* __restrict__ mb1,
                       const float* __restrict__ mw2, const float* __restrict__ mb2,
                       const float* __restrict__ mw3, const float* __restrict__ mb3,
                       float* __restrict__ out, int B){
  __shared__ float pairv[256];
  __shared__ float z1[128];
  __shared__ float z2[64];
  int r = blockIdx.x;
  int t = threadIdx.x;            // 128: wave0 = liq node, wave1 = ing node
  int w = t >> 6;
  int lane = t & 63;
  int n = w ? ing[r] : liq[r];
  float ald = aldv[n];
  float es = lrelu(al[n] + ald);
  int beg = row[n], end = row[n + 1];
  float m = es;
  for (int j = beg; j < end; ++j)
    m = fmaxf(m, lrelu(al[csr[j]] + ald));
  float ps = __expf(es - m);
  float l = ps;
  int c0 = lane * 2;
  ushort2 hv = *reinterpret_cast<const ushort2*>(hp + (size_t)n * 128 + c0);
  float a0 = ps * bf2f(hv.x), a1 = ps * bf2f(hv.y);
  for (int j = beg; j < end; ++j){
    int s = csr[j];
    float p = __expf(lrelu(al[s] + ald) - m);
    ushort2 v = *reinterpret_cast<const ushort2*>(hp + (size_t)s * 128 + c0);
    a0 = fmaf(p, bf2f(v.x), a0);
    a1 = fmaf(p, bf2f(v.y), a1);
    l += p;
  }
  float inv = 1.f / l;
  pairv[w * 128 + c0]     = a0 * inv + bias[c0];
  pairv[w * 128 + c0 + 1] = a1 * inv + bias[c0 + 1];
  __syncthreads();
  float acc1 = mb1[t];
  for (int k = 0; k < 256; ++k) acc1 = fmaf(pairv[k], mw1[k * 128 + t], acc1);
  z1[t] = fmaxf(acc1, 0.f);
  __syncthreads();
  if (t < 64){
    float a2 = mb2[t];
    for (int k = 0; k < 128; ++k) a2 = fmaf(z1[k], mw2[k * 64 + t], a2);
    z2[t] = fmaxf(a2, 0.f);
  }
  __syncthreads();
  if (t < 64){
    float p = z2[t] * mw3[t];
    #pragma unroll
    for (int off = 32; off >= 1; off >>= 1) p += __shfl_xor(p, off);
    if (t == 0) out[r] = 1.f / (1.f + __expf(-(p + mb3[0])));
  }
  (void)B;
}

// ---------------- launch ----------------
extern "C" void kernel_launch(void* const* d_in, const int* in_sizes, int n_in,
                              void* d_out, int out_size, void* d_ws, size_t ws_size,
                              hipStream_t stream){
  const float* x   = (const float*)d_in[0];
  const int*   ei  = (const int*)  d_in[1];
  const int*   liq = (const int*)  d_in[2];
  const int*   ing = (const int*)  d_in[3];
  const float* W1  = (const float*)d_in[4];
  const float* as1 = (const float*)d_in[5];
  const float* ad1 = (const float*)d_in[6];
  const float* b1  = (const float*)d_in[7];
  const float* W2  = (const float*)d_in[8];
  const float* as2 = (const float*)d_in[9];
  const float* ad2 = (const float*)d_in[10];
  const float* b2  = (const float*)d_in[11];
  const float* W3  = (const float*)d_in[12];
  const float* as3 = (const float*)d_in[13];
  const float* ad3 = (const float*)d_in[14];
  const float* b3  = (const float*)d_in[15];
  const float* mw1 = (const float*)d_in[16];
  const float* mb1 = (const float*)d_in[17];
  const float* mw2 = (const float*)d_in[18];
  const float* mb2 = (const float*)d_in[19];
  const float* mw3 = (const float*)d_in[20];
  const float* mb3 = (const float*)d_in[21];
  float* out = (float*)d_out;

  const int N = in_sizes[0] / 64;      // 25000
  const int E = in_sizes[1] / 2;       // 200000
  const int B = in_sizes[2];           // 4096
  const int* srcp = ei;
  const int* dstp = ei + E;

  char* w = (char*)d_ws;
  auto alloc = [&](size_t bytes) -> char* {
    char* p = w;
    w += (bytes + 255) & ~(size_t)255;
    return p;
  };
  unsigned short* P    = (unsigned short*)alloc((size_t)N * 1024 * 2);  // Php / G / P3
  unsigned short* Hb   = (unsigned short*)alloc((size_t)N * 1024 * 2);
  unsigned short* xb   = (unsigned short*)alloc((size_t)N * 64 * 2);
  unsigned short* Wt1  = (unsigned short*)alloc((size_t)1024 * 64 * 2);
  unsigned short* Wt2  = (unsigned short*)alloc((size_t)1024 * 1024 * 2);
  unsigned short* Wt3  = (unsigned short*)alloc((size_t)128 * 1024 * 2);
  float* ALS  = (float*)alloc((size_t)N * 8 * 4);
  float* ALD  = (float*)alloc((size_t)N * 8 * 4);
  float* alpha= (float*)alloc((size_t)E * 8 * 4);
  float* alps = (float*)alloc((size_t)N * 8 * 4);
  float* invl = (float*)alloc((size_t)N * 8 * 4);
  float* ws1  = (float*)alloc((size_t)64 * 16 * 4);
  int*   row  = (int*)  alloc((size_t)(N + 1) * 4);
  int*   cntcur = (int*)alloc((size_t)2 * N * 4);
  int*   cnt  = cntcur;
  int*   cur  = cntcur + N;
  int*   aux  = (int*)  alloc((size_t)256 * 4);
  int*   csr  = (int*)  alloc((size_t)E * 4);
  unsigned short* G = P;   // alias: G[N,512] lives in P until layer-2 GEMM overwrites
  (void)ws_size; (void)n_in; (void)out_size;

  // fused conversions + layer-1 fold (one launch)
  int nx = N * 64;
  int nxb = (nx + 2047) / 2048;
  k_prep<<<nxb + 64 + 1024 + 128 + 64, 256, 0, stream>>>(
      x, xb, nx, nxb, W1, Wt1, W2, Wt2, W3, Wt3, as1, ad1, ws1);

  // CSR build
  hipMemsetAsync(cntcur, 0, (size_t)2 * N * 4, stream);
  int eb = (E + 255) / 256;
  int nb = (N + 255) / 256;
  k_count<<<eb, 256, 0, stream>>>(dstp, cnt, E);
  k_blockscan<<<nb, 256, 0, stream>>>(cnt, row, aux, N);
  k_addoff<<<nb, 256, 0, stream>>>(aux, row, N);
  k_scatter<<<eb, 256, 0, stream>>>(srcp, dstp, row, cur, csr, E);

  const int mt  = (N + 127) / 128;     // 196
  const int mt2 = (N + 255) / 256;     // 98
  const int smb8 = (N * 8 + 255) / 256;

  // ---- layer 1: logits from x, softmax precompute, weighted gather, project ----
  k_logits1<<<(N + 31) / 32, 256, 0, stream>>>(xb, ws1, ALS, ALD, N);
  k_sm<8,0><<<smb8, 256, 0, stream>>>(ALS, ALD, row, csr, alpha, alps, invl, N, E);
  k_gat_x<<<(N + 3) / 4, 256, 0, stream>>>(xb, alpha, alps, invl, row, csr, G, N);
  k_gemm_g<<<8 * mt, 256, 0, stream>>>(G, Wt1, b1, Hb, N);

  // ---- layer 2: single-buffer 2-blocks/CU GEMM (head-major out) + softmax + XCD gather ----
  k_gemm256s<<<4 * mt2, 512, 0, stream>>>(Hb, Wt2, P, as2, ad2, ALS, ALD, N, 1024, 1024, 4);
  k_sm<8,1><<<smb8, 256, 0, stream>>>(ALS, ALD, row, csr, alpha, alps, invl, N, E);
  k_gat2h<<<8 * ((N + 15) / 16), 256, 0, stream>>>(P, alpha, alps, invl, row, csr, b2, Hb, N, E);

  // ---- layer 3: Hb @ W3 (1 head) + fused gather/MLP for used nodes only ----
  k_gemm_fused<1><<<1 * mt, 256, 0, stream>>>(Hb, Wt3, P, as3, ad3, ALS, ALD, N, 128, 1024, 1);
  k_pair<<<B, 128, 0, stream>>>(P, ALS, ALD, row, csr, b3, liq, ing,
                                mw1, mb1, mw2, mb2, mw3, mb3, out, B);
}